// Round 4
// baseline (511.229 us; speedup 1.0000x reference)
//
#include <hip/hip_runtime.h>
#include <stdint.h>

// Problem constants (fixed by the reference):
#define Bq      64
#define Nq      256
#define Hq      8
#define DHq     64
#define TOTALq  16384    // B*N
#define NTq     131072   // H*TOTAL
#define Dq      512      // H*DH

typedef __attribute__((ext_vector_type(8))) short short8;
typedef __attribute__((ext_vector_type(4))) float floatx4;

__device__ __forceinline__ unsigned short f2bf(float f) {
    union { float f; unsigned int u; } c; c.f = f;
    unsigned int u = c.u;
    return (unsigned short)((u + 0x7fffu + ((u >> 16) & 1u)) >> 16);
}
__device__ __forceinline__ float bf2f(unsigned short u) {
    union { unsigned int u; float f; } c; c.u = ((unsigned int)u) << 16;
    return c.f;
}

// ---------------------------------------------------------------------------
// Graph structure: degree -> dinv; dense per-sample P (64 x 256 x 256)
// ---------------------------------------------------------------------------

__global__ void count_deg_kernel(const int* __restrict__ dstp, int* __restrict__ cnt, int E) {
    int e = blockIdx.x * 256 + threadIdx.x;
    if (e < E) atomicAdd(&cnt[dstp[e]], 1);
}

__global__ void dinv_kernel(const int* __restrict__ cnt, float* __restrict__ dinv_n) {
    int v = blockIdx.x * 256 + threadIdx.x;
    if (v < TOTALq) {
        int c = cnt[v];
        dinv_n[v] = (c > 0) ? rsqrtf((float)c) : 0.0f;
    }
}

__global__ void pscatter_kernel(const int* __restrict__ srcp, const int* __restrict__ dstp,
                                const float* __restrict__ dinv_n, float* __restrict__ Pf, int E) {
    int e = blockIdx.x * 256 + threadIdx.x;
    if (e >= E) return;
    int s = srcp[e], d = dstp[e];
    int g = d >> 8;
    atomicAdd(&Pf[((size_t)g << 16) + ((size_t)(d & 255) << 8) + (s & 255)],
              -(dinv_n[s] * dinv_n[d]));
}

__global__ void pconv_kernel(const float* __restrict__ Pf, unsigned short* __restrict__ Pb) {
    int i = (blockIdx.x * 256 + threadIdx.x) * 4;
    float4 v = *(const float4*)(Pf + i);
    unsigned int lo = (unsigned int)f2bf(v.x) | ((unsigned int)f2bf(v.y) << 16);
    unsigned int hi = (unsigned int)f2bf(v.z) | ((unsigned int)f2bf(v.w) << 16);
    *(uint2*)(Pb + i) = make_uint2(lo, hi);
}

// ---------------------------------------------------------------------------
// oeh (16384 x 512 fp32) -> X0_t (512 x 16384 bf16), transposed
// ---------------------------------------------------------------------------
__global__ void x0t_kernel(const float* __restrict__ X, unsigned short* __restrict__ Xt) {
    __shared__ float tile[64 * 68];
    int t = threadIdx.x;
    int n0 = blockIdx.x * 64, c0 = blockIdx.y * 64;
#pragma unroll
    for (int it = 0; it < 4; ++it) {
        int idx = it * 256 + t;
        int nr = idx >> 4, sub = idx & 15;
        float4 v = *(const float4*)(X + (size_t)(n0 + nr) * 512 + c0 + sub * 4);
        *(float4*)(&tile[nr * 68 + sub * 4]) = v;
    }
    __syncthreads();
#pragma unroll
    for (int it = 0; it < 2; ++it) {
        int idx = it * 256 + t;
        int cr = idx >> 3, sub = idx & 7;
        unsigned int pk[4];
#pragma unroll
        for (int q = 0; q < 4; ++q) {
            unsigned short a = f2bf(tile[(sub * 8 + q * 2 + 0) * 68 + cr]);
            unsigned short b = f2bf(tile[(sub * 8 + q * 2 + 1) * 68 + cr]);
            pk[q] = (unsigned int)a | ((unsigned int)b << 16);
        }
        *(uint4*)(Xt + (size_t)(c0 + cr) * 16384 + n0 + sub * 8) =
            make_uint4(pk[0], pk[1], pk[2], pk[3]);
    }
}

// bf16 transpose: Tt (512 x 16384) -> Tn (16384 x 512). grid (256, 8)
__global__ void trn_kernel(const unsigned short* __restrict__ Tt, unsigned short* __restrict__ Tn) {
    __shared__ unsigned short tile[64 * 72];
    int t = threadIdx.x;
    int n0 = blockIdx.x * 64, c0 = blockIdx.y * 64;
#pragma unroll
    for (int it = 0; it < 2; ++it) {
        int idx = it * 256 + t;
        int cr = idx >> 3, sub = idx & 7;
        uint4 v = *(const uint4*)(Tt + (size_t)(c0 + cr) * 16384 + n0 + sub * 8);
        *(uint4*)(&tile[cr * 72 + sub * 8]) = v;
    }
    __syncthreads();
#pragma unroll
    for (int it = 0; it < 2; ++it) {
        int idx = it * 256 + t;
        int nr = idx >> 3, sub = idx & 7;
        unsigned int pk[4];
#pragma unroll
        for (int q = 0; q < 4; ++q) {
            unsigned short a = tile[(sub * 8 + q * 2 + 0) * 72 + nr];
            unsigned short b = tile[(sub * 8 + q * 2 + 1) * 72 + nr];
            pk[q] = (unsigned int)a | ((unsigned int)b << 16);
        }
        *(uint4*)(Tn + (size_t)(n0 + nr) * 512 + c0 + sub * 8) =
            make_uint4(pk[0], pk[1], pk[2], pk[3]);
    }
}

// W_cheb (4 x 64 x 64, [k][j][n]) -> WchT bf16 [k][n][j]
__global__ void wchebt_kernel(const float* __restrict__ W, unsigned short* __restrict__ WT) {
    int idx = blockIdx.x * 256 + threadIdx.x;
    int k = idx >> 12, rem = idx & 4095;
    int n = rem >> 6, j = rem & 63;
    WT[idx] = f2bf(W[(k << 12) + (j << 6) + n]);
}

// ---------------------------------------------------------------------------
// Coefficient pipeline, split for parallelism.
// p1: colsum partial (grid 512 x 4);  p2: ssum partial;  fin: per-graph tail
// ---------------------------------------------------------------------------
__global__ void coeff_p1(const float* __restrict__ attn, float* __restrict__ colsum) {
    int g = blockIdx.x, rb = blockIdx.y, j = threadIdx.x;
    int h = g >> 6, b = g & 63;
    const float* A = attn + (size_t)(b * Hq + h) * 65536 + (size_t)rb * 64 * 256;
    float cs = 0.0f;
#pragma unroll 8
    for (int i = 0; i < 64; ++i) cs += A[i * 256 + j];
    atomicAdd(&colsum[g * 256 + j], cs);
}

__global__ void coeff_p2(const float* __restrict__ attn, const float* __restrict__ colsum,
                         float* __restrict__ ssum) {
    __shared__ float dvL[64];
    int g = blockIdx.x, rb = blockIdx.y, j = threadIdx.x;
    int h = g >> 6, b = g & 63;
    const float* A = attn + (size_t)(b * Hq + h) * 65536 + (size_t)rb * 64 * 256;
    if (j < 64) dvL[j] = rsqrtf(colsum[g * 256 + rb * 64 + j] + 1.0f);
    __syncthreads();
    float sj = 0.0f;
#pragma unroll 8
    for (int i = 0; i < 64; ++i) sj += dvL[i] * A[i * 256 + j];
    atomicAdd(&ssum[g * 256 + j], sj);
}

__global__ void coeff_fin(const float* __restrict__ colsum, const float* __restrict__ ssum,
                          const float* __restrict__ Wg, const float* __restrict__ bg,
                          const float* __restrict__ Wlin, const float* __restrict__ blin,
                          float* __restrict__ coeff) {
    __shared__ float red[16];
    int g = blockIdx.x, j = threadIdx.x;
    float dv = rsqrtf(colsum[g * 256 + j] + 1.0f);
    float sj = dv * (dv + ssum[g * 256 + j]);
    float xc[4];
#pragma unroll
    for (int c = 0; c < 4; ++c) {
        float wr = Wg[0 * 4 + c] + Wg[1 * 4 + c] + Wg[2 * 4 + c] + Wg[3 * 4 + c];
        xc[c] = tanhf(sj * wr + bg[c]);
    }
    int lane = j & 63, wv = j >> 6;
#pragma unroll
    for (int c = 0; c < 4; ++c) {
        float v = xc[c];
#pragma unroll
        for (int o = 32; o >= 1; o >>= 1) v += __shfl_down(v, o, 64);
        if (lane == 0) red[wv * 4 + c] = v;
    }
    __syncthreads();
    if (j < 4) {
        float gap[4];
#pragma unroll
        for (int c = 0; c < 4; ++c)
            gap[c] = (red[0 + c] + red[4 + c] + red[8 + c] + red[12 + c]) * (1.0f / 256.0f);
        float v = blin[j];
#pragma unroll
        for (int c = 0; c < 4; ++c) v += gap[c] * Wlin[c * 4 + j];
        coeff[g * 4 + j] = v;
    }
}

// ---------------------------------------------------------------------------
// Chebyshev propagation, dense per-sample MFMA GEMM.
// grid (64 samples, 4 row-blocks of 64, 4 col-blocks of 128); BK=32
// ---------------------------------------------------------------------------
__global__ __launch_bounds__(256, 4)
void cheb_prop(const unsigned short* __restrict__ Pb,
               const unsigned short* __restrict__ Tc,
               const unsigned short* __restrict__ Tp,
               unsigned short* __restrict__ Tn, int first) {
    __shared__ unsigned short A_lds[64 * 40];   // 5 KB
    __shared__ unsigned short B_lds[128 * 40];  // 10 KB
    const int b = blockIdx.x, mb = blockIdx.y, cb = blockIdx.z;
    const int tid = threadIdx.x, lane = tid & 63, wv = tid >> 6;
    const int wr = wv & 1, wc = wv >> 1, quad = lane >> 4, l15 = lane & 15;
    const unsigned short* Pbase = Pb + ((size_t)b << 16) + (size_t)mb * 64 * 256;

    floatx4 acc[2][4];
#pragma unroll
    for (int rt = 0; rt < 2; ++rt)
#pragma unroll
        for (int ct = 0; ct < 4; ++ct) acc[rt][ct] = (floatx4){0.f, 0.f, 0.f, 0.f};

    for (int kt = 0; kt < 8; ++kt) {
        const int kc = kt * 32;
        __syncthreads();
        {
            int row = tid >> 2, sub = tid & 3;
            *(uint4*)(A_lds + row * 40 + sub * 8) =
                *(const uint4*)(Pbase + row * 256 + kc + sub * 8);
        }
#pragma unroll
        for (int it = 0; it < 2; ++it) {
            int idx = it * 256 + tid;
            int row = idx >> 2, sub = idx & 3;
            *(uint4*)(B_lds + row * 40 + sub * 8) =
                *(const uint4*)(Tc + (size_t)(cb * 128 + row) * 16384 + b * 256 + kc + sub * 8);
        }
        __syncthreads();
        short8 af[2], bfr[4];
#pragma unroll
        for (int rt = 0; rt < 2; ++rt)
            af[rt] = *(const short8*)(A_lds + (wr * 32 + rt * 16 + l15) * 40 + quad * 8);
#pragma unroll
        for (int ct = 0; ct < 4; ++ct)
            bfr[ct] = *(const short8*)(B_lds + (wc * 64 + ct * 16 + l15) * 40 + quad * 8);
#pragma unroll
        for (int rt = 0; rt < 2; ++rt)
#pragma unroll
            for (int ct = 0; ct < 4; ++ct)
                acc[rt][ct] = __builtin_amdgcn_mfma_f32_16x16x32_bf16(af[rt], bfr[ct],
                                                                     acc[rt][ct], 0, 0, 0);
    }
#pragma unroll
    for (int rt = 0; rt < 2; ++rt)
#pragma unroll
        for (int ct = 0; ct < 4; ++ct) {
            int col = cb * 128 + wc * 64 + ct * 16 + l15;
            int m = mb * 64 + wr * 32 + rt * 16 + quad * 4;
            size_t base = (size_t)col * 16384 + b * 256 + m;
            float v[4];
            if (first) {
#pragma unroll
                for (int i = 0; i < 4; ++i) v[i] = acc[rt][ct][i];
            } else {
                uint2 tp = *(const uint2*)(Tp + base);
                v[0] = 2.0f * acc[rt][ct][0] - bf2f((unsigned short)(tp.x & 0xffff));
                v[1] = 2.0f * acc[rt][ct][1] - bf2f((unsigned short)(tp.x >> 16));
                v[2] = 2.0f * acc[rt][ct][2] - bf2f((unsigned short)(tp.y & 0xffff));
                v[3] = 2.0f * acc[rt][ct][3] - bf2f((unsigned short)(tp.y >> 16));
            }
            unsigned int lo = (unsigned int)f2bf(v[0]) | ((unsigned int)f2bf(v[1]) << 16);
            unsigned int hi = (unsigned int)f2bf(v[2]) | ((unsigned int)f2bf(v[3]) << 16);
            *(uint2*)(Tn + base) = make_uint2(lo, hi);
        }
}

// ---------------------------------------------------------------------------
// filtb[(n*B+b)*512 + h*64 + c] = bf16( b_cheb[c] + sum_k ck * (T_k @ W_cheb[k]) )
// grid (64 samples, 8 heads); 256 thr
// ---------------------------------------------------------------------------
__global__ __launch_bounds__(256, 2)
void filt_kernel(const float* __restrict__ oeh,
                 const unsigned short* __restrict__ T1n, const unsigned short* __restrict__ T2n,
                 const unsigned short* __restrict__ T3n, const unsigned short* __restrict__ WchT,
                 const float* __restrict__ coeff, const float* __restrict__ bch,
                 unsigned short* __restrict__ filtb) {
    __shared__ unsigned short A_lds[256 * 72];  // 36 KB
    __shared__ unsigned short W_lds[64 * 72];   // 9 KB
    const int b = blockIdx.x, h = blockIdx.y;
    const int tid = threadIdx.x, lane = tid & 63, wv = tid >> 6;
    const int quad = lane >> 4, l15 = lane & 15;

    floatx4 acc[4][4];
#pragma unroll
    for (int rt = 0; rt < 4; ++rt)
#pragma unroll
        for (int ct = 0; ct < 4; ++ct) acc[rt][ct] = (floatx4){0.f, 0.f, 0.f, 0.f};

    for (int k = 0; k < 4; ++k) {
        float ck = coeff[(h * Bq + b) * 4 + k];
        __syncthreads();
        if (k == 0) {
#pragma unroll
            for (int it = 0; it < 8; ++it) {
                int idx = it * 256 + tid;
                int row = idx >> 3, sub = idx & 7;
                const float* sp = oeh + (size_t)(b * 256 + row) * 512 + h * 64 + sub * 8;
                float4 v0 = *(const float4*)sp;
                float4 v1 = *(const float4*)(sp + 4);
                unsigned int p0 = (unsigned int)f2bf(v0.x * ck) | ((unsigned int)f2bf(v0.y * ck) << 16);
                unsigned int p1 = (unsigned int)f2bf(v0.z * ck) | ((unsigned int)f2bf(v0.w * ck) << 16);
                unsigned int p2 = (unsigned int)f2bf(v1.x * ck) | ((unsigned int)f2bf(v1.y * ck) << 16);
                unsigned int p3 = (unsigned int)f2bf(v1.z * ck) | ((unsigned int)f2bf(v1.w * ck) << 16);
                *(uint4*)(A_lds + row * 72 + sub * 8) = make_uint4(p0, p1, p2, p3);
            }
        } else {
            const unsigned short* Tk = (k == 1) ? T1n : (k == 2) ? T2n : T3n;
#pragma unroll
            for (int it = 0; it < 8; ++it) {
                int idx = it * 256 + tid;
                int row = idx >> 3, sub = idx & 7;
                uint4 tv = *(const uint4*)(Tk + (size_t)(b * 256 + row) * 512 + h * 64 + sub * 8);
                unsigned int w[4] = {tv.x, tv.y, tv.z, tv.w};
                unsigned int o[4];
#pragma unroll
                for (int q = 0; q < 4; ++q) {
                    float lo = bf2f((unsigned short)(w[q] & 0xffff)) * ck;
                    float hi = bf2f((unsigned short)(w[q] >> 16)) * ck;
                    o[q] = (unsigned int)f2bf(lo) | ((unsigned int)f2bf(hi) << 16);
                }
                *(uint4*)(A_lds + row * 72 + sub * 8) = make_uint4(o[0], o[1], o[2], o[3]);
            }
        }
#pragma unroll
        for (int it = 0; it < 2; ++it) {
            int idx = it * 256 + tid;
            int r = idx >> 3, sub = idx & 7;
            *(uint4*)(W_lds + r * 72 + sub * 8) =
                *(const uint4*)(WchT + k * 4096 + r * 64 + sub * 8);
        }
        __syncthreads();
#pragma unroll
        for (int kk = 0; kk < 2; ++kk) {
            short8 af[4], bfr[4];
#pragma unroll
            for (int rt = 0; rt < 4; ++rt)
                af[rt] = *(const short8*)(A_lds + (wv * 64 + rt * 16 + l15) * 72 + kk * 32 + quad * 8);
#pragma unroll
            for (int ct = 0; ct < 4; ++ct)
                bfr[ct] = *(const short8*)(W_lds + (ct * 16 + l15) * 72 + kk * 32 + quad * 8);
#pragma unroll
            for (int rt = 0; rt < 4; ++rt)
#pragma unroll
                for (int ct = 0; ct < 4; ++ct)
                    acc[rt][ct] = __builtin_amdgcn_mfma_f32_16x16x32_bf16(af[rt], bfr[ct],
                                                                         acc[rt][ct], 0, 0, 0);
        }
    }
#pragma unroll
    for (int rt = 0; rt < 4; ++rt)
#pragma unroll
        for (int ct = 0; ct < 4; ++ct) {
            int coln = ct * 16 + l15;
            float bias = bch[coln];
#pragma unroll
            for (int i = 0; i < 4; ++i) {
                int m = wv * 64 + rt * 16 + quad * 4 + i;
                size_t r = (size_t)m * 64 + b;
                filtb[r * 512 + h * 64 + coln] = f2bf(acc[rt][ct][i] + bias);
            }
        }
}

// ---------------------------------------------------------------------------
// W_cat transpose+convert: W (1024x512 fp32) -> Wt (512x1024 bf16)
// ---------------------------------------------------------------------------
__global__ void wt_kernel(const float* __restrict__ W, unsigned short* __restrict__ Wt) {
    __shared__ float tile[64][65];
    int t = threadIdx.x;
    int k0 = blockIdx.x * 64;
    int c0 = blockIdx.y * 64;
#pragma unroll
    for (int it = 0; it < 16; ++it) {
        int idx = it * 256 + t;
        int kr = idx >> 6, cc = idx & 63;
        tile[kr][cc] = W[(size_t)(k0 + kr) * 512 + c0 + cc];
    }
    __syncthreads();
#pragma unroll
    for (int it = 0; it < 16; ++it) {
        int idx = it * 256 + t;
        int cr = idx >> 6, kk = idx & 63;
        Wt[(size_t)(c0 + cr) * 1024 + k0 + kk] = f2bf(tile[kk][cr]);
    }
}

// ---------------------------------------------------------------------------
// MFMA GEMM (M=16384, K=1024, N=512) + fused LayerNorm, v2.
// BM=32 -> grid 512 (2 blocks/CU). B fragments direct from global (Wt in L2).
// A tile double-buffered in LDS with register prefetch. Register-LN epilogue.
// ---------------------------------------------------------------------------
__global__ __launch_bounds__(256, 2)
void gemm_ln_mfma(const float* __restrict__ outp, const unsigned short* __restrict__ filtb,
                  const unsigned short* __restrict__ Wt, const float* __restrict__ bcat,
                  const float* __restrict__ gamma, const float* __restrict__ beta,
                  float* __restrict__ out) {
    __shared__ unsigned short A_lds[2][32 * 40];  // 2 x 2.5 KB
    __shared__ float red_s[4 * 32];
    __shared__ float red_ss[4 * 32];
    __shared__ float mu_l[32], rs_l[32];

    const int tid = threadIdx.x;
    const int lane = tid & 63;
    const int wv = tid >> 6;
    const int quad = lane >> 4;
    const int l15 = lane & 15;
    const int r0 = blockIdx.x * 32;

    floatx4 acc[2][8];
#pragma unroll
    for (int rt = 0; rt < 2; ++rt)
#pragma unroll
        for (int ct = 0; ct < 8; ++ct)
            acc[rt][ct] = (floatx4){0.f, 0.f, 0.f, 0.f};

    float bc[8], gm[8], bt2[8];
#pragma unroll
    for (int ct = 0; ct < 8; ++ct) {
        int col = wv * 128 + ct * 16 + l15;
        bc[ct] = bcat[col];
        gm[ct] = gamma[col];
        bt2[ct] = beta[col];
    }

    const int arow = tid >> 3;   // 0..31
    const int akp  = tid & 7;    // 4 k's each (uint2 / float4)
    const float* aout = outp + (size_t)(r0 + arow) * 512 + akp * 4;
    const unsigned short* afl = filtb + (size_t)(r0 + arow) * 512 + akp * 4;

    // prologue: stage kt=0 (fp32 source)
    {
        float4 v = *(const float4*)(aout);
        uint2 p;
        p.x = (unsigned int)f2bf(v.x) | ((unsigned int)f2bf(v.y) << 16);
        p.y = (unsigned int)f2bf(v.z) | ((unsigned int)f2bf(v.w) << 16);
        *(uint2*)(&A_lds[0][arow * 40 + akp * 4]) = p;
    }

    for (int kt = 0; kt < 32; ++kt) {
        const int kc1 = (kt + 1) * 32;
        float4 gaf;
        uint2 gab;
        const bool more = (kt < 31);
        if (more) {
            if (kc1 < 512) gaf = *(const float4*)(aout + kc1);
            else gab = *(const uint2*)(afl + (kc1 - 512));
        }
        __syncthreads();
        short8 afr[2], bfr[8];
#pragma unroll
        for (int rt = 0; rt < 2; ++rt)
            afr[rt] = *(const short8*)(&A_lds[kt & 1][(rt * 16 + l15) * 40 + quad * 8]);
#pragma unroll
        for (int ct = 0; ct < 8; ++ct)
            bfr[ct] = *(const short8*)(Wt + (size_t)(wv * 128 + ct * 16 + l15) * 1024
                                       + kt * 32 + quad * 8);
#pragma unroll
        for (int rt = 0; rt < 2; ++rt)
#pragma unroll
            for (int ct = 0; ct < 8; ++ct)
                acc[rt][ct] = __builtin_amdgcn_mfma_f32_16x16x32_bf16(afr[rt], bfr[ct],
                                                                     acc[rt][ct], 0, 0, 0);
        if (more) {
            uint2 p;
            if (kc1 < 512) {
                p.x = (unsigned int)f2bf(gaf.x) | ((unsigned int)f2bf(gaf.y) << 16);
                p.y = (unsigned int)f2bf(gaf.z) | ((unsigned int)f2bf(gaf.w) << 16);
            } else {
                p = gab;
            }
            *(uint2*)(&A_lds[(kt + 1) & 1][arow * 40 + akp * 4]) = p;
        }
    }

    // ---- register LayerNorm epilogue ----
    float s_[2][4], ss_[2][4];
#pragma unroll
    for (int rt = 0; rt < 2; ++rt)
#pragma unroll
        for (int i = 0; i < 4; ++i) {
            float s = 0.0f, ss = 0.0f;
#pragma unroll
            for (int ct = 0; ct < 8; ++ct) {
                float v = acc[rt][ct][i] + bc[ct];
                s += v; ss += v * v;
            }
#pragma unroll
            for (int o = 1; o < 16; o <<= 1) {
                s += __shfl_xor(s, o, 64);
                ss += __shfl_xor(ss, o, 64);
            }
            s_[rt][i] = s; ss_[rt][i] = ss;
        }
    if (l15 == 0) {
#pragma unroll
        for (int rt = 0; rt < 2; ++rt)
#pragma unroll
            for (int i = 0; i < 4; ++i) {
                int row = rt * 16 + quad * 4 + i;
                red_s[wv * 32 + row] = s_[rt][i];
                red_ss[wv * 32 + row] = ss_[rt][i];
            }
    }
    __syncthreads();
    if (tid < 32) {
        float s = red_s[tid] + red_s[32 + tid] + red_s[64 + tid] + red_s[96 + tid];
        float ss = red_ss[tid] + red_ss[32 + tid] + red_ss[64 + tid] + red_ss[96 + tid];
        float mu = s * (1.0f / 512.0f);
        float var = ss * (1.0f / 512.0f) - mu * mu;
        mu_l[tid] = mu;
        rs_l[tid] = rsqrtf(var + 1e-5f);
    }
    __syncthreads();
#pragma unroll
    for (int rt = 0; rt < 2; ++rt)
#pragma unroll
        for (int i = 0; i < 4; ++i) {
            int row = rt * 16 + quad * 4 + i;
            float mu = mu_l[row], rs = rs_l[row];
            float* orow = out + (size_t)(r0 + row) * 512;
#pragma unroll
            for (int ct = 0; ct < 8; ++ct) {
                int col = wv * 128 + ct * 16 + l15;
                float v = acc[rt][ct][i] + bc[ct];
                orow[col] = (v - mu) * rs * gm[ct] + bt2[ct];
            }
        }
}

// ---------------------------------------------------------------------------
// Launch
// ---------------------------------------------------------------------------
extern "C" void kernel_launch(void* const* d_in, const int* in_sizes, int n_in,
                              void* d_out, int out_size, void* d_ws, size_t ws_size,
                              hipStream_t stream) {
    const float* output       = (const float*)d_in[0];
    const float* attn         = (const float*)d_in[1];
    const float* oeh          = (const float*)d_in[2];
    const int*   edge_index   = (const int*)d_in[3];
    const float* W_gcn        = (const float*)d_in[6];
    const float* b_gcn        = (const float*)d_in[7];
    const float* W_lin        = (const float*)d_in[8];
    const float* b_lin        = (const float*)d_in[9];
    const float* W_cheb       = (const float*)d_in[10];
    const float* b_cheb       = (const float*)d_in[11];
    const float* W_cat        = (const float*)d_in[12];
    const float* b_cat        = (const float*)d_in[13];
    const float* gamma        = (const float*)d_in[14];
    const float* beta         = (const float*)d_in[15];
    float* out = (float*)d_out;

    const int E = in_sizes[3] / 2;
    const int* srcp = edge_index;
    const int* dstp = edge_index + E;

    uint8_t* ws = (uint8_t*)d_ws;
    size_t cur = 0;
    auto alloc = [&](size_t bytes) -> void* {
        void* p = ws + cur;
        cur += (bytes + 255) & ~(size_t)255;
        return p;
    };
    int*   cnt     = (int*)alloc(TOTALq * sizeof(int));
    float* dinv_n  = (float*)alloc(TOTALq * sizeof(float));
    float* Pf      = (float*)alloc((size_t)64 * 65536 * sizeof(float));     // 16.8 MB
    unsigned short* Pb   = (unsigned short*)alloc((size_t)64 * 65536 * 2);  //  8.4 MB
    float* coeff   = (float*)alloc(512 * 4 * sizeof(float));
    unsigned short* X0_t = (unsigned short*)alloc((size_t)512 * 16384 * 2); // 16.8 MB
    unsigned short* T1_t = (unsigned short*)alloc((size_t)512 * 16384 * 2);
    unsigned short* T2_t = (unsigned short*)alloc((size_t)512 * 16384 * 2);
    unsigned short* T3_t = (unsigned short*)alloc((size_t)512 * 16384 * 2);
    unsigned short* WchT = (unsigned short*)alloc(4 * 64 * 64 * 2);
    unsigned short* Wt   = (unsigned short*)alloc((size_t)Dq * 1024 * 2);   //  1 MB
    unsigned short* filtb= (unsigned short*)alloc((size_t)TOTALq * Dq * 2); // 16.8 MB
    float* colsum  = (float*)alloc(512 * 256 * sizeof(float));              // 0.5 MB
    float* ssum    = (float*)alloc(512 * 256 * sizeof(float));              // 0.5 MB
    // aliases into dead regions (lifetimes by launch order):
    unsigned short* T1_n = (unsigned short*)Pf;   // Pf dead after pconv
    unsigned short* T2_n = X0_t;                  // X0_t dead after prop2
    unsigned short* T3_n = T1_t;                  // T1_t dead after prop3 + trn(T1)
    (void)ws_size; (void)n_in; (void)out_size;

    hipMemsetAsync(cnt, 0, TOTALq * sizeof(int), stream);
    hipMemsetAsync(Pf, 0, (size_t)64 * 65536 * sizeof(float), stream);
    hipMemsetAsync(colsum, 0, 2 * 512 * 256 * sizeof(float), stream);  // colsum+ssum contiguous

    count_deg_kernel<<<(E + 255) / 256, 256, 0, stream>>>(dstp, cnt, E);
    dinv_kernel<<<TOTALq / 256, 256, 0, stream>>>(cnt, dinv_n);
    pscatter_kernel<<<(E + 255) / 256, 256, 0, stream>>>(srcp, dstp, dinv_n, Pf, E);
    pconv_kernel<<<4096, 256, 0, stream>>>(Pf, Pb);

    x0t_kernel<<<dim3(256, 8), 256, 0, stream>>>(oeh, X0_t);
    wt_kernel<<<dim3(16, 8), 256, 0, stream>>>(W_cat, Wt);
    wchebt_kernel<<<64, 256, 0, stream>>>(W_cheb, WchT);

    coeff_p1<<<dim3(512, 4), 256, 0, stream>>>(attn, colsum);
    coeff_p2<<<dim3(512, 4), 256, 0, stream>>>(attn, colsum, ssum);
    coeff_fin<<<512, 256, 0, stream>>>(colsum, ssum, W_gcn, b_gcn, W_lin, b_lin, coeff);

    dim3 pg(64, 4, 4);
    cheb_prop<<<pg, 256, 0, stream>>>(Pb, X0_t, nullptr, T1_t, 1);
    cheb_prop<<<pg, 256, 0, stream>>>(Pb, T1_t, X0_t, T2_t, 0);
    cheb_prop<<<pg, 256, 0, stream>>>(Pb, T2_t, T1_t, T3_t, 0);

    trn_kernel<<<dim3(256, 8), 256, 0, stream>>>(T1_t, T1_n);
    trn_kernel<<<dim3(256, 8), 256, 0, stream>>>(T2_t, T2_n);
    trn_kernel<<<dim3(256, 8), 256, 0, stream>>>(T3_t, T3_n);

    filt_kernel<<<dim3(64, 8), 256, 0, stream>>>(oeh, T1_n, T2_n, T3_n, WchT, coeff,
                                                 b_cheb, filtb);

    gemm_ln_mfma<<<TOTALq / 32, 256, 0, stream>>>(output, filtb, Wt, b_cat,
                                                  gamma, beta, out);
}